// Round 9
// baseline (233.011 us; speedup 1.0000x reference)
//
#include <hip/hip_runtime.h>

#define SLOT_B 20480                   // 10 px x 2KB fp32
#define RING_B (6*SLOT_B)              // 122880
#define OROW_B 16384                   // 16 px x 512 bf16
#define OROW_OFF RING_B
#define SMEM_T (RING_B + 2*OROW_B)     // 155648

typedef __attribute__((ext_vector_type(8))) short bf16x8;
typedef __attribute__((ext_vector_type(4))) float f32x4;
typedef __attribute__((ext_vector_type(2))) float f32x2;
typedef __attribute__((ext_vector_type(4))) int   s32x4;
typedef __attribute__((ext_vector_type(4))) unsigned int u32x4;

__device__ __forceinline__ short f2bf(float f) {
  union { float f; unsigned u; } v; v.f = f;
  unsigned r = v.u + 0x7FFFu + ((v.u >> 16) & 1u);   // RNE
  return (short)(r >> 16);
}

__global__ __launch_bounds__(1024) void bconv_kernel(
    const float* __restrict__ x, const float* __restrict__ wts,
    const float* __restrict__ bias, const int* __restrict__ bin,
    const int* __restrict__ bout, float* __restrict__ out)
{
  extern __shared__ char smem[];
  char* orow0 = smem + OROW_OFF;

  const int t = threadIdx.x, lane = t & 63, g = t >> 6;
  const int g4 = lane >> 4, n16 = lane & 15;
  const int m_r = n16 >> 3, m_c = n16 & 7;     // MFMA m -> (row,col) in 2x8 tile
  const int bid = blockIdx.x;                   // 256 = b*16 + strip*2 + seg
  const int b = bid >> 4, strip = (bid >> 1) & 7, seg = bid & 1;
  const int hs = seg * 32, w0 = strip * 8;
  const int hmax = hs + 32;

  // inverse permutation (transient in orow region)
  unsigned short* pos_tab = (unsigned short*)orow0;
  if (t < 512) pos_tab[bin[t]] = (unsigned short)t;
  __syncthreads();
  const int u = t & 255, qg = t >> 8;           // thread owns channels 2u,2u+1
  const int wA = pos_tab[2 * u], wB = pos_tab[2 * u + 1];

  // weight fragments (B elem j <-> ci = g4*8+j)
  bf16x8 wf[9][2];
  {
    const float* Wg = wts + g * 9216;
#pragma unroll
    for (int tap = 0; tap < 9; ++tap)
#pragma unroll
      for (int nt = 0; nt < 2; ++nt) {
        bf16x8 f;
#pragma unroll
        for (int j = 0; j < 8; ++j)
          f[j] = f2bf(Wg[(tap * 32 + g4 * 8 + j) * 32 + nt * 16 + n16]);
        wf[tap][nt] = f;
      }
  }
  const int ob0 = bout[g * 32 + n16] * 2;       // bf16 scatter byte offsets
  const int ob1 = bout[g * 32 + 16 + n16] * 2;
  const int sxor = g4 << 4;

  const int fr = g >> 3, fc = g & 7, fkey = g >> 2;
  const f32x4 bias0 = *(const f32x4*)(bias + lane * 8);
  const f32x4 bias1 = *(const f32x4*)(bias + lane * 8 + 4);

  // staging constants: group qg owns pixel-slots pc = qg+4i (2 rows x 10 cols)
  int strb[5], stgc[5], stwA[5], stwB[5];
#pragma unroll
  for (int i = 0; i < 5; ++i) {
    const int pc = qg + 4 * i;
    const int rb = (pc >= 10) ? 1 : 0;
    const int c = pc - 10 * rb;
    strb[i] = rb;
    stgc[i] = w0 - 1 + c;
    const int X = (c & 7) << 2;                  // float-index XOR swizzle
    stwA[i] = c * 2048 + ((wA ^ X) << 2);
    stwB[i] = c * 2048 + ((wB ^ X) << 2);
  }
  const float* xb = x + ((size_t)b << 21);

#define LOADP(row0, sv)                                                      \
  _Pragma("unroll")                                                          \
  for (int i = 0; i < 5; ++i) {                                              \
    const int row_ = (row0) + strb[i];                                       \
    f32x2 v_ = {0.f, 0.f};                                                   \
    if (row_ >= 0 && row_ <= 63 && row_ <= hmax && stgc[i] >= 0 &&           \
        stgc[i] <= 63)                                                       \
      v_ = *(const f32x2*)(xb + (((size_t)(row_ * 64 + stgc[i])) << 9) +     \
                           2 * u);                                           \
    sv[i] = v_;                                                              \
  }

#define WRITEP(row0, sv)                                                     \
  _Pragma("unroll")                                                          \
  for (int i = 0; i < 5; ++i) {                                              \
    const int row_ = (row0) + strb[i];                                       \
    if (row_ <= hmax) {                                                      \
      char* sl_ = smem + ((row_ + 12) % 6) * SLOT_B;                         \
      *(float*)(sl_ + stwA[i]) = sv[i][0];                                   \
      *(float*)(sl_ + stwB[i]) = sv[i][1];                                   \
    }                                                                        \
  }

#define FLUSH(row0, bi)                                                      \
  {                                                                          \
    const char* buf_ = orow0 + (bi) * OROW_B;                                \
    const s32x4 rv = *(const s32x4*)(buf_ + g * 1024 + ((lane ^ fkey) << 4));\
    f32x4 o0, o1;                                                            \
    o0[0] = fmaxf(__uint_as_float(((unsigned)rv[0]) << 16) + bias0[0], 0.f); \
    o0[1] = fmaxf(__uint_as_float(((unsigned)rv[0]) & 0xffff0000u) + bias0[1], 0.f); \
    o0[2] = fmaxf(__uint_as_float(((unsigned)rv[1]) << 16) + bias0[2], 0.f); \
    o0[3] = fmaxf(__uint_as_float(((unsigned)rv[1]) & 0xffff0000u) + bias0[3], 0.f); \
    o1[0] = fmaxf(__uint_as_float(((unsigned)rv[2]) << 16) + bias1[0], 0.f); \
    o1[1] = fmaxf(__uint_as_float(((unsigned)rv[2]) & 0xffff0000u) + bias1[1], 0.f); \
    o1[2] = fmaxf(__uint_as_float(((unsigned)rv[3]) << 16) + bias1[2], 0.f); \
    o1[3] = fmaxf(__uint_as_float(((unsigned)rv[3]) & 0xffff0000u) + bias1[3], 0.f); \
    float* dst_ = out + (((size_t)((b * 64 + (row0) + fr) * 64 + w0 + fc)) << 9) \
                  + lane * 8;                                                \
    *(f32x4*)dst_ = o0;                                                      \
    *(f32x4*)(dst_ + 4) = o1;                                                \
  }

  // prologue: stage rows hs-1..hs+2 (halo rows/cols written as zeros)
  {
    f32x2 p0v[5], p1v[5];
    LOADP(hs - 1, p0v)
    LOADP(hs + 1, p1v)
    WRITEP(hs - 1, p0v)
    WRITEP(hs + 1, p1v)
  }
  asm volatile("s_waitcnt lgkmcnt(0)\ns_barrier" ::: "memory");

  int p = 0;
  const int qs = g * 128 + g4 * 32;
  for (int h = hs; h < hs + 32; h += 2) {
    // P0: issue coalesced staging loads for rows h+3,h+4 (consumed post-MFMA)
    f32x2 sv[5];
    LOADP(h + 3, sv)

    // P2: MFMA, 9 taps; A = 2 swizzled fp32 ds_read_b128 + truncation-pack bf16
    f32x4 a0 = {0, 0, 0, 0}, a1 = {0, 0, 0, 0};
#pragma unroll
    for (int dh = 0; dh < 3; ++dh) {
      const int grow = h + m_r + dh - 1;
      const char* rbp = smem + ((grow + 6) % 6) * SLOT_B;
#pragma unroll
      for (int dw = 0; dw < 3; ++dw) {
        const int cs = m_c + dw;
        const char* ap = rbp + cs * 2048;
        const int ax = qs ^ ((cs & 7) << 4);
        const u32x4 lu = *(const u32x4*)(ap + ax);
        const u32x4 hu = *(const u32x4*)(ap + (ax ^ 16));
        union { unsigned uu[4]; bf16x8 v; } A;
        A.uu[0] = (lu[0] >> 16) | (lu[1] & 0xffff0000u);
        A.uu[1] = (lu[2] >> 16) | (lu[3] & 0xffff0000u);
        A.uu[2] = (hu[0] >> 16) | (hu[1] & 0xffff0000u);
        A.uu[3] = (hu[2] >> 16) | (hu[3] & 0xffff0000u);
        a0 = __builtin_amdgcn_mfma_f32_16x16x32_bf16(A.v, wf[dh * 3 + dw][0], a0, 0, 0, 0);
        a1 = __builtin_amdgcn_mfma_f32_16x16x32_bf16(A.v, wf[dh * 3 + dw][1], a1, 0, 0, 0);
      }
    }

    // P2.5: staging writes (slots h+3,h+4 — disjoint from read window h-1..h+2)
    WRITEP(h + 3, sv)

    // P3: scatter D (bf16 via verified f2bf) into orow[p]; pixel m = g4*4+rr
    {
      char* ob = orow0 + p * OROW_B;
#pragma unroll
      for (int rr = 0; rr < 4; ++rr) {
        const int m = g4 * 4 + rr;
        *(short*)(ob + m * 1024 + (ob0 ^ sxor)) = f2bf(a0[rr]);
        *(short*)(ob + m * 1024 + (ob1 ^ sxor)) = f2bf(a1[rr]);
      }
    }

    // P4: flush rows h-2,h-1 from orow[p^1] (stores never waited at barriers)
    if (h > hs) FLUSH(h - 2, p ^ 1)

    asm volatile("s_waitcnt lgkmcnt(0)\ns_barrier" ::: "memory");
    p ^= 1;
  }

  // epilogue: flush rows hs+30, hs+31
  FLUSH(hs + 30, p ^ 1)
}

extern "C" void kernel_launch(void* const* d_in, const int* in_sizes, int n_in,
                              void* d_out, int out_size, void* d_ws, size_t ws_size,
                              hipStream_t stream) {
  const float* x    = (const float*)d_in[0];
  const float* wts  = (const float*)d_in[1];
  const float* bias = (const float*)d_in[2];
  const int*   bin  = (const int*)d_in[3];
  const int*   bout = (const int*)d_in[4];
  float* out = (float*)d_out;
  (void)in_sizes; (void)n_in; (void)out_size; (void)d_ws; (void)ws_size;

  bconv_kernel<<<dim3(256), dim3(1024), SMEM_T, stream>>>(x, wts, bias, bin, bout, out);
}